// Round 1
// baseline (38.999 us; speedup 1.0000x reference)
//
#include <hip/hip_runtime.h>
#include <math.h>

// Voxelized chamfer loss:
//   vox(c) = trunc((c - off) / 0.05), off = (-3,-3,-1)
//   loss = mean_i min_j ||vx_i - vy_j||^2 + mean_j min_i ||...||^2
// All voxel coords are small integers -> distances are exact integers in fp32.

constexpr int NPTS   = 4096;            // N (points per batch)
constexpr int BLK    = 256;             // threads per block
constexpr int PPB    = 32;              // points handled per block
constexpr int NCHUNK = 8;               // threads cooperating per point
constexpr int CHUNK  = NPTS / NCHUNK;   // candidates per thread (512)

__global__ __launch_bounds__(BLK) void chamfer_min_kernel(
    const float* __restrict__ preds,
    const float* __restrict__ gts,
    float* __restrict__ partials,
    int B, int N)
{
    __shared__ __align__(16) float sx[NPTS];
    __shared__ __align__(16) float sy[NPTS];
    __shared__ __align__(16) float sz[NPTS];
    __shared__ float red[BLK];

    const int t = threadIdx.x;
    const int tilesPer = N / PPB;          // 128
    const int blocksPerDir = B * tilesPer; // 512
    int bid = blockIdx.x;
    const int dir = bid / blocksPerDir;    // 0: pred->gt, 1: gt->pred
    bid -= dir * blocksPerDir;
    const int b = bid / tilesPer;
    const int tile = bid - b * tilesPer;

    const float* __restrict__ xb = (dir == 0 ? preds : gts) + (size_t)b * N * 3;
    const float* __restrict__ yb = (dir == 0 ? gts  : preds) + (size_t)b * N * 3;

    // Stage + voxelize the full candidate set (SoA in LDS).
    for (int cand = t; cand < N; cand += BLK) {
        const float vx = yb[cand * 3 + 0];
        const float vy = yb[cand * 3 + 1];
        const float vz = yb[cand * 3 + 2];
        sx[cand] = truncf((vx + 3.0f) / 0.05f);
        sy[cand] = truncf((vy + 3.0f) / 0.05f);
        sz[cand] = truncf((vz + 1.0f) / 0.05f);
    }

    // This thread's query point: point index p, candidate-chunk c.
    const int p = t & (PPB - 1);
    const int c = t >> 5;                  // 0..7
    const int pg = tile * PPB + p;
    const float px = truncf((xb[pg * 3 + 0] + 3.0f) / 0.05f);
    const float py = truncf((xb[pg * 3 + 1] + 3.0f) / 0.05f);
    const float pz = truncf((xb[pg * 3 + 2] + 1.0f) / 0.05f);

    __syncthreads();

    float m = 3.402823466e38f;
    const int j0 = c * CHUNK;
    #pragma unroll 4
    for (int j = j0; j < j0 + CHUNK; j += 4) {
        const float4 vx = *reinterpret_cast<const float4*>(&sx[j]);
        const float4 vy = *reinterpret_cast<const float4*>(&sy[j]);
        const float4 vz = *reinterpret_cast<const float4*>(&sz[j]);
        float dx, dy, dz, d;
        dx = px - vx.x; dy = py - vy.x; dz = pz - vz.x;
        d = dx * dx + dy * dy + dz * dz; m = fminf(m, d);
        dx = px - vx.y; dy = py - vy.y; dz = pz - vz.y;
        d = dx * dx + dy * dy + dz * dz; m = fminf(m, d);
        dx = px - vx.z; dy = py - vy.z; dz = pz - vz.z;
        d = dx * dx + dy * dy + dz * dz; m = fminf(m, d);
        dx = px - vx.w; dy = py - vy.w; dz = pz - vz.w;
        d = dx * dx + dy * dy + dz * dz; m = fminf(m, d);
    }

    red[t] = m;
    __syncthreads();

    // Min across the 8 chunks of each point, then sum the 32 point-mins.
    if (t < PPB) {
        float mm = red[t];
        #pragma unroll
        for (int cc = 1; cc < NCHUNK; ++cc)
            mm = fminf(mm, red[t + PPB * cc]);
        float s = mm;
        #pragma unroll
        for (int o = 16; o >= 1; o >>= 1)
            s += __shfl_xor(s, o, 64);
        if (t == 0) partials[blockIdx.x] = s;
    }
}

__global__ __launch_bounds__(256) void reduce_kernel(
    const float* __restrict__ partials, float* __restrict__ out,
    int n, float scale)
{
    __shared__ float red[256];
    const int t = threadIdx.x;
    float s = 0.0f;
    for (int i = t; i < n; i += 256) s += partials[i];
    red[t] = s;
    __syncthreads();
    for (int k = 128; k > 0; k >>= 1) {
        if (t < k) red[t] += red[t + k];
        __syncthreads();
    }
    if (t == 0) out[0] = red[0] * scale;
}

extern "C" void kernel_launch(void* const* d_in, const int* in_sizes, int n_in,
                              void* d_out, int out_size, void* d_ws, size_t ws_size,
                              hipStream_t stream)
{
    const float* preds = (const float*)d_in[0];
    const float* gts   = (const float*)d_in[1];
    float* out = (float*)d_out;
    float* partials = (float*)d_ws;   // 2*B*(N/PPB) floats = 4 KB

    const int B = 4;
    const int N = in_sizes[0] / (B * 3);   // 4096
    const int tilesPer = N / PPB;
    const int nblocks = 2 * B * tilesPer;  // 1024

    chamfer_min_kernel<<<nblocks, BLK, 0, stream>>>(preds, gts, partials, B, N);

    const float scale = 1.0f / (float)(B * N);
    reduce_kernel<<<1, 256, 0, stream>>>(partials, out, nblocks, scale);
}

// Round 2
// 34.569 us; speedup vs baseline: 1.1282x; 1.1282x over previous
//
#include <hip/hip_runtime.h>
#include <math.h>

// Voxelized chamfer loss:
//   vox(c) = trunc((c - off) / 0.05), off = (-3,-3,-1)
//   loss = mean_i min_j ||vx_i - vy_j||^2 + mean_j min_i ||...||^2
// All voxel coords are integer-valued floats (|v| < ~2^9), so every distance,
// min, and partial sum is an exact integer in fp32 -> order-independent,
// bit-exact vs the numpy reference.
//
// Structure: 1024 blocks x 256 thr. Block = (dir, batch, 32-query tile).
// Wave qg (0..3) owns 8 queries held in registers as 4 float2 pairs
// (packed fp32 math -> v_pk_*_f32). Lane cg (0..63) scans 64 of the 4096
// candidates via contiguous-across-lanes float4 LDS reads, so each LDS read
// feeds 8 query evals (8x less DS traffic than 1-query-per-thread).

typedef float v2f __attribute__((ext_vector_type(2)));

constexpr int NPTS = 4096;            // N (points per batch)
constexpr int BLK  = 256;             // threads per block
constexpr int QPB  = 32;              // queries per block
constexpr int QPW  = 8;               // queries per wave (4 packed pairs)
constexpr float FINF = 3.402823466e38f;

__device__ __forceinline__ float vox(float c, float off) {
    return truncf((c + off) / 0.05f);  // keep IEEE divide: matches reference
}

__global__ __launch_bounds__(BLK) void chamfer_min_kernel(
    const float* __restrict__ preds,
    const float* __restrict__ gts,
    float* __restrict__ partials,
    int B, int N)
{
    __shared__ __align__(16) float sx[NPTS];
    __shared__ __align__(16) float sy[NPTS];
    __shared__ __align__(16) float sz[NPTS];

    const int t = threadIdx.x;
    const int tilesPer = N / QPB;          // 128
    const int blocksPerDir = B * tilesPer; // 512
    int bid = blockIdx.x;
    const int dir = bid / blocksPerDir;    // 0: pred->gt, 1: gt->pred
    bid -= dir * blocksPerDir;
    const int b = bid / tilesPer;
    const int tile = bid - b * tilesPer;

    const float* __restrict__ xb = (dir == 0 ? preds : gts) + (size_t)b * N * 3;
    const float* __restrict__ yb = (dir == 0 ? gts  : preds) + (size_t)b * N * 3;

    // Stage + voxelize the full candidate set (SoA, linear layout).
    for (int cand = t; cand < N; cand += BLK) {
        const float a0 = yb[cand * 3 + 0];
        const float a1 = yb[cand * 3 + 1];
        const float a2 = yb[cand * 3 + 2];
        sx[cand] = vox(a0, 3.0f);
        sy[cand] = vox(a1, 3.0f);
        sz[cand] = vox(a2, 1.0f);
    }

    const int qg = t >> 6;   // wave id 0..3 -> query group
    const int cg = t & 63;   // lane -> candidate chunk

    // This wave's 8 queries, voxelized, packed into 4 float2 pairs.
    v2f qx[4], qy[4], qz[4];
    const int qbase = tile * QPB + qg * QPW;
    #pragma unroll
    for (int p = 0; p < 4; ++p) {
        const int q0 = qbase + 2 * p, q1 = q0 + 1;
        qx[p] = (v2f){ vox(xb[q0*3+0], 3.0f), vox(xb[q1*3+0], 3.0f) };
        qy[p] = (v2f){ vox(xb[q0*3+1], 3.0f), vox(xb[q1*3+1], 3.0f) };
        qz[p] = (v2f){ vox(xb[q0*3+2], 1.0f), vox(xb[q1*3+2], 1.0f) };
    }

    __syncthreads();

    v2f m[4];
    #pragma unroll
    for (int p = 0; p < 4; ++p) m[p] = (v2f){FINF, FINF};

    // Lane cg reads float4 at [jj*256 + cg*4]: 64 lanes x 16B contiguous
    // (the m134 85 B/cyc baseline pattern, no pathological conflicts).
    #pragma unroll 2
    for (int jj = 0; jj < NPTS / 256; ++jj) {
        const int base = jj * 256 + cg * 4;
        const float4 cx = *reinterpret_cast<const float4*>(&sx[base]);
        const float4 cy = *reinterpret_cast<const float4*>(&sy[base]);
        const float4 cz = *reinterpret_cast<const float4*>(&sz[base]);
        #pragma unroll
        for (int p = 0; p < 4; ++p) {
            v2f dx, dy, dz, d0, d1, d2, d3;
            dx = qx[p] - cx.x; dy = qy[p] - cy.x; dz = qz[p] - cz.x;
            d0 = dx * dx + dy * dy + dz * dz;
            dx = qx[p] - cx.y; dy = qy[p] - cy.y; dz = qz[p] - cz.y;
            d1 = dx * dx + dy * dy + dz * dz;
            dx = qx[p] - cx.z; dy = qy[p] - cy.z; dz = qz[p] - cz.z;
            d2 = dx * dx + dy * dy + dz * dz;
            dx = qx[p] - cx.w; dy = qy[p] - cy.w; dz = qz[p] - cz.w;
            d3 = dx * dx + dy * dy + dz * dz;
            // paired mins -> v_min3_f32 fusion
            m[p].x = fminf(fminf(m[p].x, d0.x), d1.x);
            m[p].x = fminf(fminf(m[p].x, d2.x), d3.x);
            m[p].y = fminf(fminf(m[p].y, d0.y), d1.y);
            m[p].y = fminf(fminf(m[p].y, d2.y), d3.y);
        }
    }

    // Min across the 64 candidate-chunks (one wave) for each of 8 queries.
    float mm[QPW];
    #pragma unroll
    for (int p = 0; p < 4; ++p) { mm[2*p] = m[p].x; mm[2*p+1] = m[p].y; }
    #pragma unroll
    for (int i = 0; i < QPW; ++i) {
        float v = mm[i];
        #pragma unroll
        for (int o = 32; o >= 1; o >>= 1)
            v = fminf(v, __shfl_xor(v, o, 64));
        mm[i] = v;
    }
    if (cg == 0) {
        float s = 0.0f;
        #pragma unroll
        for (int i = 0; i < QPW; ++i) s += mm[i];   // exact: integer values
        partials[blockIdx.x * 4 + qg] = s;
    }
}

__global__ __launch_bounds__(256) void reduce_kernel(
    const float* __restrict__ partials, float* __restrict__ out,
    int n, float scale)
{
    __shared__ float red[256];
    const int t = threadIdx.x;
    float s = 0.0f;
    for (int i = t; i < n; i += 256) s += partials[i];
    red[t] = s;
    __syncthreads();
    for (int k = 128; k > 0; k >>= 1) {
        if (t < k) red[t] += red[t + k];
        __syncthreads();
    }
    if (t == 0) out[0] = red[0] * scale;
}

extern "C" void kernel_launch(void* const* d_in, const int* in_sizes, int n_in,
                              void* d_out, int out_size, void* d_ws, size_t ws_size,
                              hipStream_t stream)
{
    const float* preds = (const float*)d_in[0];
    const float* gts   = (const float*)d_in[1];
    float* out = (float*)d_out;
    float* partials = (float*)d_ws;   // 2*B*(N/QPB)*4 floats = 16 KB

    const int B = 4;
    const int N = in_sizes[0] / (B * 3);   // 4096
    const int tilesPer = N / QPB;
    const int nblocks = 2 * B * tilesPer;  // 1024

    chamfer_min_kernel<<<nblocks, BLK, 0, stream>>>(preds, gts, partials, B, N);

    const int npart = nblocks * 4;         // 4096
    const float scale = 1.0f / (float)(B * N);
    reduce_kernel<<<1, 256, 0, stream>>>(partials, out, npart, scale);
}